// Round 1
// baseline (1469.727 us; speedup 1.0000x reference)
//
#include <hip/hip_runtime.h>

#define NN 50000
#define DD 128
#define EE 1600000

// ---------------- CSR build ----------------

__global__ void hist_kernel(const int* __restrict__ dst, int* __restrict__ deg) {
    int e = blockIdx.x * blockDim.x + threadIdx.x;
    if (e < EE) {
        int d = dst[e];
        if ((unsigned)d < (unsigned)NN) atomicAdd(&deg[d], 1);
    }
}

// one block, 1024 threads: exclusive prefix sum of deg[NN] -> rowptr[NN+1], copy to cursor
__global__ void scan_kernel(const int* __restrict__ deg, int* __restrict__ rowptr,
                            int* __restrict__ cursor) {
    const int T = 1024;
    const int CHUNK = (NN + T - 1) / T;  // 49
    __shared__ int sums[T];
    int t = threadIdx.x;
    int start = t * CHUNK;
    int local = 0;
    for (int i = 0; i < CHUNK; ++i) {
        int idx = start + i;
        if (idx < NN) local += deg[idx];
    }
    sums[t] = local;
    __syncthreads();
    // Hillis-Steele inclusive scan
    for (int off = 1; off < T; off <<= 1) {
        int v = (t >= off) ? sums[t - off] : 0;
        __syncthreads();
        sums[t] += v;
        __syncthreads();
    }
    int run = (t == 0) ? 0 : sums[t - 1];
    for (int i = 0; i < CHUNK; ++i) {
        int idx = start + i;
        if (idx < NN) {
            rowptr[idx] = run;
            cursor[idx] = run;
            run += deg[idx];
        }
    }
    if (t == T - 1) rowptr[NN] = run;
}

__global__ void fill_kernel(const int* __restrict__ src, const int* __restrict__ dst,
                            int* __restrict__ cursor, int* __restrict__ sorted_src) {
    int e = blockIdx.x * blockDim.x + threadIdx.x;
    if (e < EE) {
        int d = dst[e];
        int s = src[e];
        if ((unsigned)d < (unsigned)NN) {
            int pos = atomicAdd(&cursor[d], 1);
            sorted_src[pos] = s;
        }
    }
}

// ---------------- mean aggregation (atomic-free via CSR) ----------------
// one wave per dst row; lane handles 2 cols (float2)
__global__ void agg_kernel(const float* __restrict__ x, const int* __restrict__ rowptr,
                           const int* __restrict__ srcs, float* __restrict__ out) {
    int wave = (blockIdx.x * blockDim.x + threadIdx.x) >> 6;
    int lane = threadIdx.x & 63;
    if (wave >= NN) return;
    int beg = rowptr[wave], end = rowptr[wave + 1];
    float ax = 0.f, ay = 0.f;
    for (int j = beg; j < end; ++j) {
        int s = srcs[j];
        float2 v = *reinterpret_cast<const float2*>(&x[s * DD + lane * 2]);
        ax += v.x;
        ay += v.y;
    }
    float inv = (end > beg) ? 1.0f / (float)(end - beg) : 0.0f;
    float2 r;
    r.x = ax * inv;
    r.y = ay * inv;
    *reinterpret_cast<float2*>(&out[wave * DD + lane * 2]) = r;
}

// ---------------- fused SAGE linear: out = [relu](A1@W1 + A2@W2 + b) ----------------
// block 256 threads; 8 rows per block; thread: col c=t&127, row-group g=t>>7 (4 rows each)
template <bool RELU>
__global__ void sage_gemm_kernel(const float* __restrict__ A1, const float* __restrict__ W1,
                                 const float* __restrict__ A2, const float* __restrict__ W2,
                                 const float* __restrict__ bias, float* __restrict__ out) {
    __shared__ float a1s[8][DD];
    __shared__ float a2s[8][DD];
    int t = threadIdx.x;
    int c = t & 127;
    int g = t >> 7;
    int row0 = blockIdx.x * 8;
    for (int i = t; i < 8 * DD; i += 256) {
        int r = i >> 7, cc = i & 127;
        int rr = row0 + r;
        float v1 = 0.f, v2 = 0.f;
        if (rr < NN) {
            v1 = A1[rr * DD + cc];
            v2 = A2[rr * DD + cc];
        }
        a1s[r][cc] = v1;
        a2s[r][cc] = v2;
    }
    __syncthreads();
    float acc[4] = {0.f, 0.f, 0.f, 0.f};
    for (int k = 0; k < DD; ++k) {
        float w = W1[k * DD + c];
#pragma unroll
        for (int r = 0; r < 4; ++r) acc[r] += a1s[g * 4 + r][k] * w;
    }
    for (int k = 0; k < DD; ++k) {
        float w = W2[k * DD + c];
#pragma unroll
        for (int r = 0; r < 4; ++r) acc[r] += a2s[g * 4 + r][k] * w;
    }
    float b = bias[c];
#pragma unroll
    for (int r = 0; r < 4; ++r) {
        int rr = row0 + g * 4 + r;
        if (rr < NN) {
            float v = acc[r] + b;
            if (RELU) v = fmaxf(v, 0.f);
            out[rr * DD + c] = v;
        }
    }
}

// ---------------- final linear [N,128]@[128,2]+b ----------------
// one wave per row, lane handles 2 k's, wave-reduce
__global__ void final_kernel(const float* __restrict__ H, const float* __restrict__ Wf,
                             const float* __restrict__ bf, float* __restrict__ out) {
    int wave = (blockIdx.x * blockDim.x + threadIdx.x) >> 6;
    int lane = threadIdx.x & 63;
    if (wave >= NN) return;
    float2 h = *reinterpret_cast<const float2*>(&H[wave * DD + lane * 2]);
    int k0 = lane * 2, k1 = lane * 2 + 1;
    float a0 = h.x * Wf[k0 * 2 + 0] + h.y * Wf[k1 * 2 + 0];
    float a1 = h.x * Wf[k0 * 2 + 1] + h.y * Wf[k1 * 2 + 1];
    for (int off = 32; off; off >>= 1) {
        a0 += __shfl_down(a0, off);
        a1 += __shfl_down(a1, off);
    }
    if (lane == 0) {
        out[wave * 2 + 0] = a0 + bf[0];
        out[wave * 2 + 1] = a1 + bf[1];
    }
}

extern "C" void kernel_launch(void* const* d_in, const int* in_sizes, int n_in,
                              void* d_out, int out_size, void* d_ws, size_t ws_size,
                              hipStream_t stream) {
    const float* x_student = (const float*)d_in[0];
    const float* x_studies = (const float*)d_in[1];
    const int* ei_s2st = (const int*)d_in[2];
    const int* ei_st2s = (const int*)d_in[3];
    const float* l1_st_Wl = (const float*)d_in[4];
    const float* l1_st_b = (const float*)d_in[5];
    const float* l1_st_Wr = (const float*)d_in[6];
    const float* l1_s_Wl = (const float*)d_in[7];
    const float* l1_s_b = (const float*)d_in[8];
    const float* l1_s_Wr = (const float*)d_in[9];
    const float* l2_st_Wl = (const float*)d_in[10];
    const float* l2_st_b = (const float*)d_in[11];
    const float* l2_st_Wr = (const float*)d_in[12];
    const float* lin_W = (const float*)d_in[16];
    const float* lin_b = (const float*)d_in[17];
    float* out = (float*)d_out;

    // workspace layout
    char* ws = (char*)d_ws;
    float* agg = (float*)ws;                       // N*D
    float* hst = agg + (size_t)NN * DD;            // N*D
    float* hs = hst + (size_t)NN * DD;             // N*D (reused for layer-2 output)
    int* deg_a = (int*)(hs + (size_t)NN * DD);     // N
    int* deg_b = deg_a + NN;                       // N
    int* rowptr_a = deg_b + NN;                    // N+1
    int* rowptr_b = rowptr_a + (NN + 1);           // N+1
    int* cursor_a = rowptr_b + (NN + 1);           // N
    int* cursor_b = cursor_a + NN;                 // N
    int* sorted_a = cursor_b + NN;                 // E
    int* sorted_b = sorted_a + EE;                 // E

    const int* src_a = ei_s2st;            // s2st: src=student
    const int* dst_a = ei_s2st + EE;       // dst=studies
    const int* src_b = ei_st2s;            // st2s: src=studies
    const int* dst_b = ei_st2s + EE;       // dst=student

    // 1. build CSR for both edge types
    hipMemsetAsync(deg_a, 0, 2 * NN * sizeof(int), stream);
    int eb = (EE + 255) / 256;
    hist_kernel<<<eb, 256, 0, stream>>>(dst_a, deg_a);
    hist_kernel<<<eb, 256, 0, stream>>>(dst_b, deg_b);
    scan_kernel<<<1, 1024, 0, stream>>>(deg_a, rowptr_a, cursor_a);
    scan_kernel<<<1, 1024, 0, stream>>>(deg_b, rowptr_b, cursor_b);
    fill_kernel<<<eb, 256, 0, stream>>>(src_a, dst_a, cursor_a, sorted_a);
    fill_kernel<<<eb, 256, 0, stream>>>(src_b, dst_b, cursor_b, sorted_b);

    int aggGrid = (NN * 64 + 255) / 256;     // one wave per row
    int gemmGrid = (NN + 7) / 8;

    // 2. layer 1: h_st = relu(mean_s2st(x_student)@Wl + b + x_studies@Wr)
    agg_kernel<<<aggGrid, 256, 0, stream>>>(x_student, rowptr_a, sorted_a, agg);
    sage_gemm_kernel<true><<<gemmGrid, 256, 0, stream>>>(agg, l1_st_Wl, x_studies, l1_st_Wr,
                                                         l1_st_b, hst);
    //    h_s = relu(mean_st2s(x_studies)@Wl + b + x_student@Wr)
    agg_kernel<<<aggGrid, 256, 0, stream>>>(x_studies, rowptr_b, sorted_b, agg);
    sage_gemm_kernel<true><<<gemmGrid, 256, 0, stream>>>(agg, l1_s_Wl, x_student, l1_s_Wr,
                                                         l1_s_b, hs);

    // 3. layer 2: h_st2 = mean_s2st(h_s)@Wl + b + h_st@Wr   (output overwrites hs)
    agg_kernel<<<aggGrid, 256, 0, stream>>>(hs, rowptr_a, sorted_a, agg);
    sage_gemm_kernel<false><<<gemmGrid, 256, 0, stream>>>(agg, l2_st_Wl, hst, l2_st_Wr,
                                                          l2_st_b, hs);

    // 4. final linear
    final_kernel<<<aggGrid, 256, 0, stream>>>(hs, lin_W, lin_b, out);
}

// Round 2
// 930.302 us; speedup vs baseline: 1.5798x; 1.5798x over previous
//
#include <hip/hip_runtime.h>

#define NN 50000
#define DD 128
#define EE 1600000

typedef unsigned int uint;
typedef unsigned short ushort;

__device__ __forceinline__ ushort f2bf(float f) {
    uint u = __float_as_uint(f);
    u += 0x7fffu + ((u >> 16) & 1u);   // round-to-nearest-even
    return (ushort)(u >> 16);
}

// ---------------- CSR build ----------------

__global__ void __launch_bounds__(256) hist_kernel(const int* __restrict__ dst,
                                                   int* __restrict__ deg) {
    int e = blockIdx.x * blockDim.x + threadIdx.x;
    if (e < EE) atomicAdd(&deg[dst[e]], 1);
}

// two-level scan: per-block sums -> scan of block sums -> final exclusive scan
__global__ void __launch_bounds__(256) scan_partials_kernel(const int* __restrict__ deg,
                                                            int* __restrict__ bsum) {
    int t = threadIdx.x;
    int idx = blockIdx.x * 256 + t;
    int v = (idx < NN) ? deg[idx] : 0;
#pragma unroll
    for (int off = 32; off; off >>= 1) v += __shfl_down(v, off);
    __shared__ int wsum[4];
    if ((t & 63) == 0) wsum[t >> 6] = v;
    __syncthreads();
    if (t == 0) bsum[blockIdx.x] = wsum[0] + wsum[1] + wsum[2] + wsum[3];
}

__global__ void __launch_bounds__(256) scan_bsums_kernel(int* __restrict__ bsum, int nb) {
    int t = threadIdx.x;
    int lane = t & 63, w = t >> 6;
    int v = (t < nb) ? bsum[t] : 0;
    int inc = v;
#pragma unroll
    for (int off = 1; off < 64; off <<= 1) {
        int n = __shfl_up(inc, off);
        if (lane >= off) inc += n;
    }
    __shared__ int wsum[4];
    if (lane == 63) wsum[w] = inc;
    __syncthreads();
    int woff = 0;
#pragma unroll
    for (int i = 0; i < 4; ++i)
        if (i < w) woff += wsum[i];
    if (t < nb) bsum[t] = woff + inc - v;  // exclusive
}

__global__ void __launch_bounds__(256) scan_final_kernel(const int* __restrict__ deg,
                                                         const int* __restrict__ bsum,
                                                         int* __restrict__ rowptr,
                                                         int* __restrict__ cursor) {
    int t = threadIdx.x;
    int idx = blockIdx.x * 256 + t;
    int lane = t & 63, w = t >> 6;
    int v = (idx < NN) ? deg[idx] : 0;
    int inc = v;
#pragma unroll
    for (int off = 1; off < 64; off <<= 1) {
        int n = __shfl_up(inc, off);
        if (lane >= off) inc += n;
    }
    __shared__ int wsum[4];
    if (lane == 63) wsum[w] = inc;
    __syncthreads();
    int woff = bsum[blockIdx.x];
#pragma unroll
    for (int i = 0; i < 4; ++i)
        if (i < w) woff += wsum[i];
    int ex = woff + inc - v;
    if (idx < NN) {
        rowptr[idx] = ex;
        cursor[idx] = ex;
    } else if (idx == NN) {
        rowptr[NN] = ex;
    }
}

__global__ void __launch_bounds__(256) fill_kernel(const int* __restrict__ src,
                                                   const int* __restrict__ dst,
                                                   int* __restrict__ cursor,
                                                   int* __restrict__ sorted_src) {
    int e = blockIdx.x * blockDim.x + threadIdx.x;
    if (e < EE) {
        int pos = atomicAdd(&cursor[dst[e]], 1);
        sorted_src[pos] = src[e];
    }
}

// ---------------- f32 -> bf16 table conversion ----------------
__global__ void __launch_bounds__(256) f32_to_bf16_kernel(const float* __restrict__ in,
                                                          ushort* __restrict__ out, int n4) {
    int i = blockIdx.x * blockDim.x + threadIdx.x;
    if (i < n4) {
        float4 v = ((const float4*)in)[i];
        ushort4 o;
        o.x = f2bf(v.x);
        o.y = f2bf(v.y);
        o.z = f2bf(v.z);
        o.w = f2bf(v.w);
        ((ushort4*)out)[i] = o;
    }
}

// ---------------- mean aggregation over bf16 table ----------------
// one wave per dst row; lane handles 2 cols (one uint = 2 bf16); 8-deep pipelined gather
__global__ void __launch_bounds__(256) agg_kernel(const uint* __restrict__ xu,
                                                  const int* __restrict__ rowptr,
                                                  const int* __restrict__ srcs,
                                                  float* __restrict__ out) {
    int wid = (blockIdx.x * blockDim.x + threadIdx.x) >> 6;
    int lane = threadIdx.x & 63;
    if (wid >= NN) return;
    int beg = rowptr[wid], end = rowptr[wid + 1];
    float ax = 0.f, ay = 0.f;
    int j = beg;
    int nfull = (end - beg) >> 3;
    int ss[8];
    if (nfull > 0) {
#pragma unroll
        for (int u = 0; u < 8; ++u) ss[u] = srcs[j + u];
    }
    for (int ch = 0; ch < nfull; ++ch) {
        uint vv[8];
#pragma unroll
        for (int u = 0; u < 8; ++u) vv[u] = xu[ss[u] * 64 + lane];
        int base = j + 8;
        bool more = (ch + 1 < nfull);
        int sn[8];
#pragma unroll
        for (int u = 0; u < 8; ++u) sn[u] = more ? srcs[base + u] : 0;
#pragma unroll
        for (int u = 0; u < 8; ++u) {
            ax += __uint_as_float(vv[u] << 16);
            ay += __uint_as_float(vv[u] & 0xffff0000u);
        }
#pragma unroll
        for (int u = 0; u < 8; ++u) ss[u] = sn[u];
        j += 8;
    }
    for (; j < end; ++j) {
        int s = srcs[j];
        uint v = xu[s * 64 + lane];
        ax += __uint_as_float(v << 16);
        ay += __uint_as_float(v & 0xffff0000u);
    }
    float inv = (end > beg) ? 1.0f / (float)(end - beg) : 0.0f;
    float2 r;
    r.x = ax * inv;
    r.y = ay * inv;
    *reinterpret_cast<float2*>(&out[(size_t)wid * DD + lane * 2]) = r;
}

// ---------------- fused SAGE linear: out = [relu](A1@W1 + A2@W2 + b) ----------------
// MODE 0: f32 out + relu | MODE 1: bf16 out + relu | MODE 2: fused final linear -> [N,2] f32
// block 256; 16 rows/block (NN % 16 == 0); thread: col c=t&127, row-group g=t>>7 (8 rows)
template <int MODE>
__global__ void __launch_bounds__(256) sage_gemm_kernel(
    const float* __restrict__ A1, const float* __restrict__ W1, const float* __restrict__ A2,
    const float* __restrict__ W2, const float* __restrict__ bias, const float* __restrict__ Wf,
    const float* __restrict__ bf, void* __restrict__ out) {
    __shared__ float a1s[16][DD];
    __shared__ float a2s[16][DD];
    int t = threadIdx.x;
    int c = t & 127;
    int g = t >> 7;
    int row0 = blockIdx.x * 16;
    {
        const float4* A1v = (const float4*)(A1 + (size_t)row0 * DD);
        const float4* A2v = (const float4*)(A2 + (size_t)row0 * DD);
        float4* s1 = (float4*)a1s;
        float4* s2 = (float4*)a2s;
#pragma unroll
        for (int i = 0; i < 2; ++i) {
            s1[t + i * 256] = A1v[t + i * 256];
            s2[t + i * 256] = A2v[t + i * 256];
        }
    }
    __syncthreads();
    float acc[8] = {0.f, 0.f, 0.f, 0.f, 0.f, 0.f, 0.f, 0.f};
    for (int k = 0; k < DD; k += 4) {
        float4 a1[8], a2[8];
#pragma unroll
        for (int r = 0; r < 8; ++r) {
            a1[r] = *(const float4*)&a1s[g * 8 + r][k];
            a2[r] = *(const float4*)&a2s[g * 8 + r][k];
        }
        float w10 = W1[(k + 0) * DD + c], w11 = W1[(k + 1) * DD + c];
        float w12 = W1[(k + 2) * DD + c], w13 = W1[(k + 3) * DD + c];
        float w20 = W2[(k + 0) * DD + c], w21 = W2[(k + 1) * DD + c];
        float w22 = W2[(k + 2) * DD + c], w23 = W2[(k + 3) * DD + c];
#pragma unroll
        for (int r = 0; r < 8; ++r) {
            acc[r] += a1[r].x * w10 + a1[r].y * w11 + a1[r].z * w12 + a1[r].w * w13;
            acc[r] += a2[r].x * w20 + a2[r].y * w21 + a2[r].z * w22 + a2[r].w * w23;
        }
    }
    float b = bias[c];
    if (MODE == 2) {
        float wf0 = Wf[c * 2 + 0], wf1 = Wf[c * 2 + 1];
        __shared__ float red[4][8][2];
        int w = t >> 6, lane = t & 63;
#pragma unroll
        for (int r = 0; r < 8; ++r) {
            float v = acc[r] + b;
            float p0 = v * wf0, p1 = v * wf1;
#pragma unroll
            for (int off = 32; off; off >>= 1) {
                p0 += __shfl_down(p0, off);
                p1 += __shfl_down(p1, off);
            }
            if (lane == 0) {
                red[w][r][0] = p0;
                red[w][r][1] = p1;
            }
        }
        __syncthreads();
        if (t < 32) {
            int gg = t >> 4;
            int rr = (t >> 1) & 7;
            int o = t & 1;
            float v = red[gg * 2][rr][o] + red[gg * 2 + 1][rr][o] + bf[o];
            ((float*)out)[(size_t)(row0 + gg * 8 + rr) * 2 + o] = v;
        }
    } else {
#pragma unroll
        for (int r = 0; r < 8; ++r) {
            float v = fmaxf(acc[r] + b, 0.f);
            size_t idx = (size_t)(row0 + g * 8 + r) * DD + c;
            if (MODE == 0)
                ((float*)out)[idx] = v;
            else
                ((ushort*)out)[idx] = f2bf(v);
        }
    }
}

extern "C" void kernel_launch(void* const* d_in, const int* in_sizes, int n_in,
                              void* d_out, int out_size, void* d_ws, size_t ws_size,
                              hipStream_t stream) {
    const float* x_student = (const float*)d_in[0];
    const float* x_studies = (const float*)d_in[1];
    const int* ei_s2st = (const int*)d_in[2];
    const int* ei_st2s = (const int*)d_in[3];
    const float* l1_st_Wl = (const float*)d_in[4];
    const float* l1_st_b = (const float*)d_in[5];
    const float* l1_st_Wr = (const float*)d_in[6];
    const float* l1_s_Wl = (const float*)d_in[7];
    const float* l1_s_b = (const float*)d_in[8];
    const float* l1_s_Wr = (const float*)d_in[9];
    const float* l2_st_Wl = (const float*)d_in[10];
    const float* l2_st_b = (const float*)d_in[11];
    const float* l2_st_Wr = (const float*)d_in[12];
    const float* lin_W = (const float*)d_in[16];
    const float* lin_b = (const float*)d_in[17];
    float* out = (float*)d_out;

    // workspace layout
    char* ws = (char*)d_ws;
    float* agg = (float*)ws;                           // N*D f32
    float* hst = agg + (size_t)NN * DD;                // N*D f32
    ushort* xstu_bf = (ushort*)(hst + (size_t)NN * DD);  // N*D bf16
    ushort* xsts_bf = xstu_bf + (size_t)NN * DD;       // N*D bf16
    ushort* hs_bf = xsts_bf + (size_t)NN * DD;         // N*D bf16
    int* deg_a = (int*)(hs_bf + (size_t)NN * DD);      // N
    int* deg_b = deg_a + NN;                           // N
    int* rowptr_a = deg_b + NN;                        // N+1
    int* rowptr_b = rowptr_a + (NN + 1);               // N+1
    int* cursor_a = rowptr_b + (NN + 1);               // N
    int* cursor_b = cursor_a + NN;                     // N
    int* bsum_a = cursor_b + NN;                       // 256
    int* bsum_b = bsum_a + 256;                        // 256
    int* sorted_a = bsum_b + 256;                      // E
    int* sorted_b = sorted_a + EE;                     // E

    const int* src_a = ei_s2st;       // s2st: src=student
    const int* dst_a = ei_s2st + EE;  // dst=studies
    const int* src_b = ei_st2s;       // st2s: src=studies
    const int* dst_b = ei_st2s + EE;  // dst=student

    const int eb = (EE + 255) / 256;
    const int nb = (NN + 256) / 256;  // 196 blocks covers idx 0..NN inclusive
    const int cvGrid = (NN * DD / 4 + 255) / 256;
    const int aggGrid = (NN * 64 + 255) / 256;
    const int gemmGrid = NN / 16;  // 3125

    // 0. bf16 feature tables
    f32_to_bf16_kernel<<<cvGrid, 256, 0, stream>>>(x_student, xstu_bf, NN * DD / 4);
    f32_to_bf16_kernel<<<cvGrid, 256, 0, stream>>>(x_studies, xsts_bf, NN * DD / 4);

    // 1. build CSR for both edge types
    hipMemsetAsync(deg_a, 0, 2 * NN * sizeof(int), stream);
    hist_kernel<<<eb, 256, 0, stream>>>(dst_a, deg_a);
    hist_kernel<<<eb, 256, 0, stream>>>(dst_b, deg_b);
    scan_partials_kernel<<<nb, 256, 0, stream>>>(deg_a, bsum_a);
    scan_partials_kernel<<<nb, 256, 0, stream>>>(deg_b, bsum_b);
    scan_bsums_kernel<<<1, 256, 0, stream>>>(bsum_a, nb);
    scan_bsums_kernel<<<1, 256, 0, stream>>>(bsum_b, nb);
    scan_final_kernel<<<nb, 256, 0, stream>>>(deg_a, bsum_a, rowptr_a, cursor_a);
    scan_final_kernel<<<nb, 256, 0, stream>>>(deg_b, bsum_b, rowptr_b, cursor_b);
    fill_kernel<<<eb, 256, 0, stream>>>(src_a, dst_a, cursor_a, sorted_a);
    fill_kernel<<<eb, 256, 0, stream>>>(src_b, dst_b, cursor_b, sorted_b);

    // 2. layer 1: h_st = relu(mean_s2st(x_student)@Wl + b + x_studies@Wr)  -> f32
    agg_kernel<<<aggGrid, 256, 0, stream>>>((const uint*)xstu_bf, rowptr_a, sorted_a, agg);
    sage_gemm_kernel<0><<<gemmGrid, 256, 0, stream>>>(agg, l1_st_Wl, x_studies, l1_st_Wr,
                                                      l1_st_b, nullptr, nullptr, hst);
    //    h_s = relu(mean_st2s(x_studies)@Wl + b + x_student@Wr)  -> bf16 (gather-only use)
    agg_kernel<<<aggGrid, 256, 0, stream>>>((const uint*)xsts_bf, rowptr_b, sorted_b, agg);
    sage_gemm_kernel<1><<<gemmGrid, 256, 0, stream>>>(agg, l1_s_Wl, x_student, l1_s_Wr,
                                                      l1_s_b, nullptr, nullptr, hs_bf);

    // 3. layer 2 + fused final linear -> out [N,2]
    agg_kernel<<<aggGrid, 256, 0, stream>>>((const uint*)hs_bf, rowptr_a, sorted_a, agg);
    sage_gemm_kernel<2><<<gemmGrid, 256, 0, stream>>>(agg, l2_st_Wl, hst, l2_st_Wr,
                                                      l2_st_b, lin_W, lin_b, out);
}